// Round 1
// baseline (3290.712 us; speedup 1.0000x reference)
//
#include <hip/hip_runtime.h>
#include <hip/hip_fp16.h>

typedef _Float16 f16;
typedef _Float16 f16x8 __attribute__((ext_vector_type(8)));
typedef float    f32x4 __attribute__((ext_vector_type(4)));

#define HID 512
#define FEA 128
#define ROWSTR 129            // inputs row = 128 feat + 1 shock
#define SEQL 512
#define DEN1 64
#define NG 8                  // batch groups (16 rows each)
#define WPG 32                // workgroups per group
#define MB 16                 // batch rows per group
#define GC 16                 // gate columns per wg
#define THREADS 256
#define KTOT 640              // 512 (h via R) + 128 (x via kernel)

// workspace layout (bytes); zeroed every launch via hipMemsetAsync
#define WS_CTR    0                     // (SEQL+1)*NG u32 barrier counters
#define WS_HRING  32768                 // 2*NG*MB*HID f16 = 262144 B
#define WS_SM     (WS_HRING + 262144)   // 128 f32 shock means
#define WS_HPART  (WS_SM + 1024)        // NG*WPG*MB f32 head partials
#define WS_END    (WS_HPART + 16384)

__device__ __forceinline__ float sigmoid_f(float x) {
    x = fminf(fmaxf(x, -30.f), 30.f);
    return 1.f / (1.f + __expf(-x));
}
__device__ __forceinline__ float tanh_f(float x) {
    x = fminf(fmaxf(x, -15.f), 15.f);
    float e = __expf(2.f * x);
    return (e - 1.f) / (e + 1.f);
}

__global__ __launch_bounds__(THREADS)
void gru_fused(const float* __restrict__ inp, const float* __restrict__ Wk,
               const float* __restrict__ Rk,  const float* __restrict__ bias,
               const float* __restrict__ W1,  const float* __restrict__ b1,
               const float* __restrict__ gam, const float* __restrict__ bet,
               const float* __restrict__ mmn, const float* __restrict__ mvr,
               const float* __restrict__ W2,  const float* __restrict__ b2p,
               const float* __restrict__ Wsh, float* __restrict__ out,
               char* __restrict__ ws)
{
    __shared__ __align__(16) f16 Bl[KTOT * 48];   // 61440 B: [R;Wk] slice as B-fragments
    __shared__ float red[4096];                    // 16384 B: reductions

    const int tid  = threadIdx.x;
    const int g    = blockIdx.x & (NG - 1);   // group; bid%8 -> likely XCD-local
    const int wgk  = blockIdx.x >> 3;         // rank within group, 0..31
    const int lane = tid & 63;
    const int wave = tid >> 6;
    const int j0   = wgk * GC;                // first gate column owned

    unsigned* ctr   = (unsigned*)(ws + WS_CTR);
    f16*      hring = (f16*)(ws + WS_HRING);
    float*    smw   = (float*)(ws + WS_SM);
    float*    hpart = (float*)(ws + WS_HPART);

    // ---- stage B = [R; Wk] gate-col slice (48 cols: z,r,h) into LDS as f16 frags ----
    // frag layout: f16x8 at index ((kk>>3)*48 + c), element kk&7 ; c = tile*16 + col
    for (int idx = tid; idx < KTOT * 48; idx += THREADS) {
        int kk  = idx / 48;
        int c   = idx - kk * 48;
        int col = (c >> 4) * HID + j0 + (c & 15);
        float v = (kk < HID) ? Rk[(size_t)kk * 1536 + col]
                             : Wk[(size_t)(kk - HID) * 1536 + col];
        Bl[((size_t)(kk >> 3) * 48 + c) * 8 + (kk & 7)] = (f16)v;
    }

    // ---- shock mean: wg with wgk<16 computes batch row g*16+wgk ----
    if (wgk < MB) {
        int b = g * MB + wgk;
        float a = 0.f;
        for (int t = tid; t < SEQL; t += THREADS)
            a += inp[((size_t)b * SEQL + t) * ROWSTR + FEA];
        red[tid] = a;
        __syncthreads();
        for (int s = THREADS / 2; s > 0; s >>= 1) {
            if (tid < s) red[tid] += red[tid + s];
            __syncthreads();
        }
        if (tid == 0) smw[b] = red[0] * (1.f / SEQL);
    }

    // per-thread gate constants; thread -> (brow=tid>>4, col=tid&15)
    const int brow = tid >> 4;
    const int jcol = j0 + (tid & 15);
    const float bZ  = bias[jcol]           + bias[1536 + jcol];
    const float bR  = bias[512 + jcol]     + bias[1536 + 512 + jcol];
    const float bXH = bias[1024 + jcol];                   // input bias, cand (outside r*)
    const float bHH = bias[1536 + 1024 + jcol];            // recurrent bias, cand (inside r*)

    const int arow  = lane & 15;    // A-frag row (batch row within block)
    const int ahalf = lane >> 4;    // A-frag k-subchunk

    float xa[4][8];                 // wave 3: prefetched x floats for current step
    if (wave == 3) {
        const float* xb = inp + ((size_t)(g * MB + arow) * SEQL + 0) * ROWSTR + ahalf * 8;
        #pragma unroll
        for (int s = 0; s < 4; ++s)
            #pragma unroll
            for (int q = 0; q < 8; ++q)
                xa[s][q] = xb[s * 32 + q];
    }

    float hold = 0.f;               // this thread's own h element (h0 = 0)
    __syncthreads();                // Bl ready

    for (int t = 0; t < SEQL; ++t) {
        const int cur = t & 1;
        const f16* hc = hring + ((size_t)cur * NG + g) * MB * HID + (size_t)arow * HID;

        f32x4 aZ = {0,0,0,0}, aR = {0,0,0,0}, aH = {0,0,0,0}, aX = {0,0,0,0};

        if (wave < 3) {             // k-steps 5w..5w+4, all from h
            f16x8 af[5];
            #pragma unroll
            for (int s = 0; s < 5; ++s)
                af[s] = *(const f16x8*)(hc + (wave * 5 + s) * 32 + ahalf * 8);
            #pragma unroll
            for (int s = 0; s < 5; ++s) {
                int ks = wave * 5 + s;
                const f16x8* bp = ((const f16x8*)Bl) + (ks * 4 + ahalf) * 48 + (lane & 15);
                f16x8 bz = bp[0], br = bp[16], bh = bp[32];
                aZ = __builtin_amdgcn_mfma_f32_16x16x32_f16(af[s], bz, aZ, 0, 0, 0);
                aR = __builtin_amdgcn_mfma_f32_16x16x32_f16(af[s], br, aR, 0, 0, 0);
                aH = __builtin_amdgcn_mfma_f32_16x16x32_f16(af[s], bh, aH, 0, 0, 0);
            }
        } else {                    // wave 3: k-step 15 from h, 16..19 from x
            f16x8 af0 = *(const f16x8*)(hc + 15 * 32 + ahalf * 8);
            f16x8 afx[4];
            #pragma unroll
            for (int s = 0; s < 4; ++s) {
                f16x8 a;
                #pragma unroll
                for (int q = 0; q < 8; ++q) a[q] = (f16)xa[s][q];
                afx[s] = a;
            }
            {   // prefetch next step's x (read-only; safe across fences)
                int tt = (t + 1 < SEQL) ? t + 1 : SEQL - 1;
                const float* xb = inp + ((size_t)(g * MB + arow) * SEQL + tt) * ROWSTR + ahalf * 8;
                #pragma unroll
                for (int s = 0; s < 4; ++s)
                    #pragma unroll
                    for (int q = 0; q < 8; ++q)
                        xa[s][q] = xb[s * 32 + q];
            }
            {
                const f16x8* bp = ((const f16x8*)Bl) + (15 * 4 + ahalf) * 48 + (lane & 15);
                aZ = __builtin_amdgcn_mfma_f32_16x16x32_f16(af0, bp[0],  aZ, 0, 0, 0);
                aR = __builtin_amdgcn_mfma_f32_16x16x32_f16(af0, bp[16], aR, 0, 0, 0);
                aH = __builtin_amdgcn_mfma_f32_16x16x32_f16(af0, bp[32], aH, 0, 0, 0);
            }
            #pragma unroll
            for (int s = 0; s < 4; ++s) {
                int ks = 16 + s;
                const f16x8* bp = ((const f16x8*)Bl) + (ks * 4 + ahalf) * 48 + (lane & 15);
                aZ = __builtin_amdgcn_mfma_f32_16x16x32_f16(afx[s], bp[0],  aZ, 0, 0, 0);
                aR = __builtin_amdgcn_mfma_f32_16x16x32_f16(afx[s], bp[16], aR, 0, 0, 0);
                aX = __builtin_amdgcn_mfma_f32_16x16x32_f16(afx[s], bp[32], aX, 0, 0, 0);
            }
        }

        // stash K-split partials: D layout col=lane&15, row=(lane>>4)*4+i
        #pragma unroll
        for (int i = 0; i < 4; ++i) {
            int ridx = (ahalf * 4 + i) * 16 + (lane & 15);
            red[wave * 1024 +       ridx] = aZ[i];
            red[wave * 1024 + 256 + ridx] = aR[i];
            red[wave * 1024 + 512 + ridx] = aH[i];
        }
        if (wave == 3) {
            #pragma unroll
            for (int i = 0; i < 4; ++i) {
                int ridx = (ahalf * 4 + i) * 16 + (lane & 15);
                red[3 * 1024 + 768 + ridx] = aX[i];
            }
        }
        __syncthreads();

        // reduce + gates; thread owns element (brow, jcol); note ridx identity == tid
        float zp = red[tid] + red[1024 + tid] + red[2048 + tid] + red[3072 + tid];
        float rp = red[256 + tid] + red[1280 + tid] + red[2304 + tid] + red[3328 + tid];
        float hp = red[512 + tid] + red[1536 + tid] + red[2560 + tid] + red[3584 + tid];
        float xp = red[3840 + tid];

        float z = sigmoid_f(zp + bZ);
        float r = sigmoid_f(rp + bR);
        float hcand = tanh_f((xp + bXH) + r * (hp + bHH));
        float hnew = z * hold + (1.f - z) * hcand;
        f16 h16 = (f16)hnew;
        hold = (float)h16;   // keep own copy identical to what others read
        hring[(((size_t)(cur ^ 1) * NG + g) * MB + brow) * HID + jcol] = h16;

        // group barrier: release stores -> arrive -> spin -> acquire
        __syncthreads();     // drains each wave's vmcnt before thread0 fences
        if (tid == 0) {
            __builtin_amdgcn_fence(__ATOMIC_RELEASE, "agent");
            unsigned* c9 = ctr + (size_t)t * NG + g;
            unsigned old = __hip_atomic_fetch_add(c9, 1u, __ATOMIC_RELAXED, __HIP_MEMORY_SCOPE_AGENT);
            if (old != WPG - 1)
                while (__hip_atomic_load(c9, __ATOMIC_RELAXED, __HIP_MEMORY_SCOPE_AGENT) < WPG)
                    __builtin_amdgcn_s_sleep(1);
            __builtin_amdgcn_fence(__ATOMIC_ACQUIRE, "agent");
        }
        __syncthreads();
    }

    // ---- head: state=(h + shock_mean*W_shock); relu(state@W1+b1); BN; @W2+b2 ----
    // final h is in ring slot 0 (t=511 wrote cur^1 = 0)
    const f16* hf = hring + (size_t)g * MB * HID;
    const int sub = tid & 15;
    const int c0 = wgk * 2;          // this wg's two DENSE1 columns
    float p0 = 0.f, p1 = 0.f, w0 = 0.f, w1 = 0.f;
    for (int i = 0; i < 32; ++i) {
        int k = sub * 32 + i;
        float hv = (float)hf[(size_t)brow * HID + k];
        float a0 = W1[(size_t)k * DEN1 + c0];
        float a1 = W1[(size_t)k * DEN1 + c0 + 1];
        p0 += hv * a0; p1 += hv * a1; w0 += a0; w1 += a1;   // w* = col-sums for shock term
    }
    red[tid] = p0; red[256 + tid] = w0; red[512 + tid] = p1; red[768 + tid] = w1;
    __syncthreads();
    if (tid < 32) {
        int b = tid >> 1, cc = tid & 1;
        int c = c0 + cc;
        float dot = 0.f, wsum = 0.f;
        for (int i = 0; i < 16; ++i) {
            dot  += red[cc * 512 + b * 16 + i];
            wsum += red[cc * 512 + 256 + b * 16 + i];
        }
        float sW = smw[g * MB + b] * Wsh[0];
        float d = dot + sW * wsum + b1[c];
        d = fmaxf(d, 0.f);
        d = (d - mmn[c]) * rsqrtf(mvr[c] + 0.001f) * gam[c] + bet[c];
        red[1024 + tid] = d * W2[c];
    }
    __syncthreads();
    if (tid < MB)
        hpart[((size_t)g * WPG + wgk) * MB + tid] = red[1024 + tid * 2] + red[1024 + tid * 2 + 1];
    __syncthreads();
    if (tid == 0) {
        __builtin_amdgcn_fence(__ATOMIC_RELEASE, "agent");
        unsigned* c9 = ctr + (size_t)SEQL * NG + g;
        unsigned old = __hip_atomic_fetch_add(c9, 1u, __ATOMIC_RELAXED, __HIP_MEMORY_SCOPE_AGENT);
        if (old != WPG - 1)
            while (__hip_atomic_load(c9, __ATOMIC_RELAXED, __HIP_MEMORY_SCOPE_AGENT) < WPG)
                __builtin_amdgcn_s_sleep(1);
        __builtin_amdgcn_fence(__ATOMIC_ACQUIRE, "agent");
    }
    __syncthreads();
    if (wgk == 0 && tid < MB) {
        float o = b2p[0];
        for (int k = 0; k < WPG; ++k)       // fixed order -> deterministic
            o += hpart[((size_t)g * WPG + k) * MB + tid];
        out[g * MB + tid] = o;
    }
}

extern "C" void kernel_launch(void* const* d_in, const int* in_sizes, int n_in,
                              void* d_out, int out_size, void* d_ws, size_t ws_size,
                              hipStream_t stream) {
    (void)in_sizes; (void)n_in; (void)out_size; (void)ws_size;
    const float* inp  = (const float*)d_in[0];
    const float* Wk   = (const float*)d_in[1];
    const float* Rk   = (const float*)d_in[2];
    const float* bias = (const float*)d_in[3];
    const float* W1   = (const float*)d_in[4];
    const float* b1   = (const float*)d_in[5];
    const float* gam  = (const float*)d_in[6];
    const float* bet  = (const float*)d_in[7];
    const float* mmn  = (const float*)d_in[8];
    const float* mvr  = (const float*)d_in[9];
    const float* W2   = (const float*)d_in[10];
    const float* b2p  = (const float*)d_in[11];
    const float* Wsh  = (const float*)d_in[12];

    hipMemsetAsync(d_ws, 0, WS_END, stream);   // barrier counters + h0 = 0, every launch
    hipLaunchKernelGGL(gru_fused, dim3(NG * WPG), dim3(THREADS), 0, stream,
                       inp, Wk, Rk, bias, W1, b1, gam, bet, mmn, mvr, W2, b2p, Wsh,
                       (float*)d_out, (char*)d_ws);
}

// Round 2
// 1622.126 us; speedup vs baseline: 2.0286x; 2.0286x over previous
//
#include <hip/hip_runtime.h>
#include <hip/hip_fp16.h>

typedef _Float16 f16;
typedef _Float16 f16x8 __attribute__((ext_vector_type(8)));
typedef float    f32x4 __attribute__((ext_vector_type(4)));

#define HID 512
#define FEA 128
#define ROWSTR 129            // inputs row = 128 feat + 1 shock
#define SEQL 512
#define DEN1 64
#define NG 8                  // batch groups (16 rows each)
#define WPG 32                // workgroups per group
#define MB 16                 // batch rows per group
#define GC 16                 // gate columns per wg
#define THREADS 256
#define KTOT 640              // 512 (h via R) + 128 (x via kernel)

// workspace layout (bytes); zeroed every launch via hipMemsetAsync
#define WS_CTR    0                     // (SEQL+1)*NG u32 barrier counters
#define WS_HRING  32768                 // 2*NG*MB*HID f16 = 262144 B
#define WS_SM     (WS_HRING + 262144)   // 128 f32 shock means
#define WS_HPART  (WS_SM + 1024)        // NG*WPG*MB f32 head partials
#define WS_END    (WS_HPART + 16384)

#define AT_LD(p)      __hip_atomic_load((p),  __ATOMIC_RELAXED, __HIP_MEMORY_SCOPE_AGENT)
#define AT_ST(p, v)   __hip_atomic_store((p), (v), __ATOMIC_RELAXED, __HIP_MEMORY_SCOPE_AGENT)

union HQ { unsigned long long u[2]; f16x8 v; };
union H4 { unsigned long long u; f16 h[4]; };

__device__ __forceinline__ float sigmoid_f(float x) {
    x = fminf(fmaxf(x, -30.f), 30.f);
    return 1.f / (1.f + __expf(-x));
}
__device__ __forceinline__ float tanh_f(float x) {
    x = fminf(fmaxf(x, -15.f), 15.f);
    float e = __expf(2.f * x);
    return (e - 1.f) / (e + 1.f);
}

__global__ __launch_bounds__(THREADS)
void gru_fused(const float* __restrict__ inp, const float* __restrict__ Wk,
               const float* __restrict__ Rk,  const float* __restrict__ bias,
               const float* __restrict__ W1,  const float* __restrict__ b1,
               const float* __restrict__ gam, const float* __restrict__ bet,
               const float* __restrict__ mmn, const float* __restrict__ mvr,
               const float* __restrict__ W2,  const float* __restrict__ b2p,
               const float* __restrict__ Wsh, float* __restrict__ out,
               char* __restrict__ ws)
{
    __shared__ __align__(16) f16 Bl[KTOT * 48];   // 61440 B: [R;Wk] slice as B-fragments
    __shared__ float red[4096];                    // 16384 B: reductions
    __shared__ __align__(8) f16 htile[256];        // this wg's 16x16 h-output tile

    const int tid  = threadIdx.x;
    const int g    = blockIdx.x & (NG - 1);   // group; bid%8 -> likely XCD-local
    const int wgk  = blockIdx.x >> 3;         // rank within group, 0..31
    const int lane = tid & 63;
    const int wave = tid >> 6;
    const int j0   = wgk * GC;                // first gate column owned

    unsigned* ctr   = (unsigned*)(ws + WS_CTR);
    f16*      hring = (f16*)(ws + WS_HRING);
    float*    smw   = (float*)(ws + WS_SM);
    float*    hpart = (float*)(ws + WS_HPART);

    // ---- stage B = [R; Wk] gate-col slice (48 cols: z,r,h) into LDS as f16 frags ----
    for (int idx = tid; idx < KTOT * 48; idx += THREADS) {
        int kk  = idx / 48;
        int c   = idx - kk * 48;
        int col = (c >> 4) * HID + j0 + (c & 15);
        float v = (kk < HID) ? Rk[(size_t)kk * 1536 + col]
                             : Wk[(size_t)(kk - HID) * 1536 + col];
        Bl[((size_t)(kk >> 3) * 48 + c) * 8 + (kk & 7)] = (f16)v;
    }

    // ---- shock mean: wg with wgk<16 computes batch row g*16+wgk ----
    if (wgk < MB) {
        int b = g * MB + wgk;
        float a = 0.f;
        for (int t = tid; t < SEQL; t += THREADS)
            a += inp[((size_t)b * SEQL + t) * ROWSTR + FEA];
        red[tid] = a;
        __syncthreads();
        for (int s = THREADS / 2; s > 0; s >>= 1) {
            if (tid < s) red[tid] += red[tid + s];
            __syncthreads();
        }
        if (tid == 0) smw[b] = red[0] * (1.f / SEQL);
    }

    // per-thread gate constants; thread -> (brow=tid>>4, col=tid&15)
    const int brow = tid >> 4;
    const int jcol = j0 + (tid & 15);
    const float bZ  = bias[jcol]           + bias[1536 + jcol];
    const float bR  = bias[512 + jcol]     + bias[1536 + 512 + jcol];
    const float bXH = bias[1024 + jcol];                   // input bias, cand
    const float bHH = bias[1536 + 1024 + jcol];            // recurrent bias, cand

    const int arow  = lane & 15;    // A-frag row (batch row within block)
    const int ahalf = lane >> 4;    // A-frag k-subchunk

    float xa[4][8];                 // wave 3: prefetched x floats for current step
    if (wave == 3) {
        const float* xb = inp + ((size_t)(g * MB + arow) * SEQL + 0) * ROWSTR + ahalf * 8;
        #pragma unroll
        for (int s = 0; s < 4; ++s)
            #pragma unroll
            for (int q = 0; q < 8; ++q)
                xa[s][q] = xb[s * 32 + q];
    }

    float hold = 0.f;               // this thread's own h element (h0 = 0)
    __syncthreads();                // Bl ready

    for (int t = 0; t < SEQL; ++t) {
        const int cur = t & 1;
        // u64-granular coherent view of this lane's h row in the current slot
        const unsigned long long* hq = (const unsigned long long*)
            (hring + ((size_t)cur * NG + g) * MB * HID + (size_t)arow * HID);

        f32x4 aZ = {0,0,0,0}, aR = {0,0,0,0}, aH = {0,0,0,0}, aX = {0,0,0,0};

        if (wave < 3) {             // k-steps 5w..5w+4, all from h
            f16x8 af[5];
            #pragma unroll
            for (int s = 0; s < 5; ++s) {
                int ks = wave * 5 + s;
                HQ x;
                x.u[0] = AT_LD(hq + ks * 8 + ahalf * 2);
                x.u[1] = AT_LD(hq + ks * 8 + ahalf * 2 + 1);
                af[s] = x.v;
            }
            #pragma unroll
            for (int s = 0; s < 5; ++s) {
                int ks = wave * 5 + s;
                const f16x8* bp = ((const f16x8*)Bl) + (ks * 4 + ahalf) * 48 + (lane & 15);
                f16x8 bz = bp[0], br = bp[16], bh = bp[32];
                aZ = __builtin_amdgcn_mfma_f32_16x16x32_f16(af[s], bz, aZ, 0, 0, 0);
                aR = __builtin_amdgcn_mfma_f32_16x16x32_f16(af[s], br, aR, 0, 0, 0);
                aH = __builtin_amdgcn_mfma_f32_16x16x32_f16(af[s], bh, aH, 0, 0, 0);
            }
        } else {                    // wave 3: k-step 15 from h, 16..19 from x
            HQ x0;
            x0.u[0] = AT_LD(hq + 15 * 8 + ahalf * 2);
            x0.u[1] = AT_LD(hq + 15 * 8 + ahalf * 2 + 1);
            f16x8 af0 = x0.v;
            f16x8 afx[4];
            #pragma unroll
            for (int s = 0; s < 4; ++s) {
                f16x8 a;
                #pragma unroll
                for (int q = 0; q < 8; ++q) a[q] = (f16)xa[s][q];
                afx[s] = a;
            }
            {   // prefetch next step's x (read-only; plain cached loads)
                int tt = (t + 1 < SEQL) ? t + 1 : SEQL - 1;
                const float* xb = inp + ((size_t)(g * MB + arow) * SEQL + tt) * ROWSTR + ahalf * 8;
                #pragma unroll
                for (int s = 0; s < 4; ++s)
                    #pragma unroll
                    for (int q = 0; q < 8; ++q)
                        xa[s][q] = xb[s * 32 + q];
            }
            {
                const f16x8* bp = ((const f16x8*)Bl) + (15 * 4 + ahalf) * 48 + (lane & 15);
                aZ = __builtin_amdgcn_mfma_f32_16x16x32_f16(af0, bp[0],  aZ, 0, 0, 0);
                aR = __builtin_amdgcn_mfma_f32_16x16x32_f16(af0, bp[16], aR, 0, 0, 0);
                aH = __builtin_amdgcn_mfma_f32_16x16x32_f16(af0, bp[32], aH, 0, 0, 0);
            }
            #pragma unroll
            for (int s = 0; s < 4; ++s) {
                int ks = 16 + s;
                const f16x8* bp = ((const f16x8*)Bl) + (ks * 4 + ahalf) * 48 + (lane & 15);
                aZ = __builtin_amdgcn_mfma_f32_16x16x32_f16(afx[s], bp[0],  aZ, 0, 0, 0);
                aR = __builtin_amdgcn_mfma_f32_16x16x32_f16(afx[s], bp[16], aR, 0, 0, 0);
                aX = __builtin_amdgcn_mfma_f32_16x16x32_f16(afx[s], bp[32], aX, 0, 0, 0);
            }
        }

        // stash K-split partials: D layout col=lane&15, row=(lane>>4)*4+i
        #pragma unroll
        for (int i = 0; i < 4; ++i) {
            int ridx = (ahalf * 4 + i) * 16 + (lane & 15);
            red[wave * 1024 +       ridx] = aZ[i];
            red[wave * 1024 + 256 + ridx] = aR[i];
            red[wave * 1024 + 512 + ridx] = aH[i];
        }
        if (wave == 3) {
            #pragma unroll
            for (int i = 0; i < 4; ++i) {
                int ridx = (ahalf * 4 + i) * 16 + (lane & 15);
                red[3 * 1024 + 768 + ridx] = aX[i];
            }
        }
        __syncthreads();

        // reduce + gates; thread owns element (brow, jcol); ridx identity == tid
        float zp = red[tid] + red[1024 + tid] + red[2048 + tid] + red[3072 + tid];
        float rp = red[256 + tid] + red[1280 + tid] + red[2304 + tid] + red[3328 + tid];
        float hp = red[512 + tid] + red[1536 + tid] + red[2560 + tid] + red[3584 + tid];
        float xp = red[3840 + tid];

        float z = sigmoid_f(zp + bZ);
        float r = sigmoid_f(rp + bR);
        float hcand = tanh_f((xp + bXH) + r * (hp + bHH));
        float hnew = z * hold + (1.f - z) * hcand;
        f16 h16 = (f16)hnew;
        hold = (float)h16;
        htile[brow * 16 + (tid & 15)] = h16;   // gather for wide coherent stores
        __syncthreads();

        // wave 0: publish tile as 64 x 8B coherent (L1/L2-bypass) stores, then barrier
        if (tid < 64) {
            int row = tid >> 2, q = tid & 3;
            unsigned long long val = *(const unsigned long long*)(htile + row * 16 + q * 4);
            unsigned long long* dst = (unsigned long long*)
                (hring + (((size_t)(cur ^ 1) * NG + g) * MB + row) * HID + j0 + q * 4);
            AT_ST(dst, val);
        }
        if (wave == 0) {
            asm volatile("s_waitcnt vmcnt(0)" ::: "memory");   // stores reached L3
            if (tid == 0) {
                unsigned* c9 = ctr + (size_t)t * NG + g;
                unsigned old = __hip_atomic_fetch_add(c9, 1u, __ATOMIC_RELAXED, __HIP_MEMORY_SCOPE_AGENT);
                if (old != WPG - 1)
                    while (AT_LD(c9) < WPG) {}
            }
        }
        __syncthreads();
    }

    // ---- head: state=(h + shock_mean*W_shock); relu(state@W1+b1); BN; @W2+b2 ----
    // final h is in ring slot 0 (t=511 wrote cur^1 = 0); read via coherent loads
    const unsigned long long* hfq = (const unsigned long long*)
        (hring + ((size_t)g * MB + brow) * HID);
    const int sub = tid & 15;
    const int c0 = wgk * 2;          // this wg's two DENSE1 columns
    float p0 = 0.f, p1 = 0.f, w0 = 0.f, w1 = 0.f;
    for (int c8 = 0; c8 < 8; ++c8) {
        H4 x; x.u = AT_LD(hfq + sub * 8 + c8);
        #pragma unroll
        for (int e = 0; e < 4; ++e) {
            int k = sub * 32 + c8 * 4 + e;
            float hv = (float)x.h[e];
            float a0 = W1[(size_t)k * DEN1 + c0];
            float a1 = W1[(size_t)k * DEN1 + c0 + 1];
            p0 += hv * a0; p1 += hv * a1; w0 += a0; w1 += a1;
        }
    }
    red[tid] = p0; red[256 + tid] = w0; red[512 + tid] = p1; red[768 + tid] = w1;
    __syncthreads();
    if (tid < 32) {
        int b = tid >> 1, cc = tid & 1;
        int c = c0 + cc;
        float dot = 0.f, wsum = 0.f;
        for (int i = 0; i < 16; ++i) {
            dot  += red[cc * 512 + b * 16 + i];
            wsum += red[cc * 512 + 256 + b * 16 + i];
        }
        float sW = smw[g * MB + b] * Wsh[0];
        float d = dot + sW * wsum + b1[c];
        d = fmaxf(d, 0.f);
        d = (d - mmn[c]) * rsqrtf(mvr[c] + 0.001f) * gam[c] + bet[c];
        red[1024 + tid] = d * W2[c];
    }
    __syncthreads();
    if (tid < MB)
        hpart[((size_t)g * WPG + wgk) * MB + tid] = red[1024 + tid * 2] + red[1024 + tid * 2 + 1];
    __syncthreads();
    // final heavy barrier (once): full fences so normal loads of smw/hpart are fresh
    if (tid == 0) {
        __builtin_amdgcn_fence(__ATOMIC_RELEASE, "agent");
        unsigned* c9 = ctr + (size_t)SEQL * NG + g;
        unsigned old = __hip_atomic_fetch_add(c9, 1u, __ATOMIC_RELAXED, __HIP_MEMORY_SCOPE_AGENT);
        if (old != WPG - 1)
            while (AT_LD(c9) < WPG) {}
        __builtin_amdgcn_fence(__ATOMIC_ACQUIRE, "agent");
    }
    __syncthreads();
    if (wgk == 0 && tid < MB) {
        float o = b2p[0];
        for (int k = 0; k < WPG; ++k)       // fixed order -> deterministic
            o += hpart[((size_t)g * WPG + k) * MB + tid];
        out[g * MB + tid] = o;
    }
}

extern "C" void kernel_launch(void* const* d_in, const int* in_sizes, int n_in,
                              void* d_out, int out_size, void* d_ws, size_t ws_size,
                              hipStream_t stream) {
    (void)in_sizes; (void)n_in; (void)out_size; (void)ws_size;
    const float* inp  = (const float*)d_in[0];
    const float* Wk   = (const float*)d_in[1];
    const float* Rk   = (const float*)d_in[2];
    const float* bias = (const float*)d_in[3];
    const float* W1   = (const float*)d_in[4];
    const float* b1   = (const float*)d_in[5];
    const float* gam  = (const float*)d_in[6];
    const float* bet  = (const float*)d_in[7];
    const float* mmn  = (const float*)d_in[8];
    const float* mvr  = (const float*)d_in[9];
    const float* W2   = (const float*)d_in[10];
    const float* b2p  = (const float*)d_in[11];
    const float* Wsh  = (const float*)d_in[12];

    hipMemsetAsync(d_ws, 0, WS_END, stream);   // barrier counters + h0 = 0, every launch
    hipLaunchKernelGGL(gru_fused, dim3(NG * WPG), dim3(THREADS), 0, stream,
                       inp, Wk, Rk, bias, W1, b1, gam, bet, mmn, mvr, W2, b2p, Wsh,
                       (float*)d_out, (char*)d_ws);
}

// Round 3
// 1385.717 us; speedup vs baseline: 2.3747x; 1.1706x over previous
//
#include <hip/hip_runtime.h>
#include <hip/hip_fp16.h>

typedef _Float16 f16;
typedef _Float16 f16x8 __attribute__((ext_vector_type(8)));
typedef float    f32x4 __attribute__((ext_vector_type(4)));

#define HID 512
#define FEA 128
#define ROWSTR 129            // inputs row = 128 feat + 1 shock
#define SEQL 512
#define DEN1 64
#define NG 8                  // batch groups (16 rows each)
#define WPG 32                // workgroups per group
#define MB 16                 // batch rows per group
#define GC 16                 // gate columns per wg
#define THREADS 256
#define KTOT 640              // 512 (h via R) + 128 (x via kernel)

// workspace layout (bytes); zeroed every launch via hipMemsetAsync
#define WS_CTR    0                     // NG u32 final-barrier counters
#define WS_FLG    256                   // NG*32 u32 step flags (128B per group)
#define WS_HRING  4096                  // 2*NG*MB*HID f16 = 262144 B
#define WS_SM     (WS_HRING + 262144)   // 128 f32 shock means
#define WS_HPART  (WS_SM + 1024)        // NG*WPG*MB f32 head partials
#define WS_END    (WS_HPART + 16384)

#define AT_LD(p)  __hip_atomic_load((p),  __ATOMIC_RELAXED, __HIP_MEMORY_SCOPE_AGENT)

union H4 { unsigned long long u; f16 h[4]; };

// --- device-coherent (bypass L1+L2) asm memory ops; batched, no implicit waits ---
__device__ __forceinline__ f16x8 ld_h16(const f16* p) {
    f16x8 r;
    asm volatile("global_load_dwordx4 %0, %1, off sc0 sc1" : "=v"(r) : "v"(p));
    return r;
}
__device__ __forceinline__ void st_h64(void* p, unsigned long long v) {
    asm volatile("global_store_dwordx2 %0, %1, off sc0 sc1" :: "v"(p), "v"(v) : "memory");
}
__device__ __forceinline__ unsigned ld_flag(const unsigned* p) {
    unsigned r;
    asm volatile("global_load_dword %0, %1, off sc0 sc1" : "=v"(r) : "v"(p) : "memory");
    asm volatile("s_waitcnt vmcnt(0)" ::: "memory");
    return r;
}
__device__ __forceinline__ void st_flag(unsigned* p, unsigned v) {
    asm volatile("global_store_dword %0, %1, off sc0 sc1" :: "v"(p), "v"(v) : "memory");
}
__device__ __forceinline__ void wait_vm0() {
    asm volatile("s_waitcnt vmcnt(0)" ::: "memory");
    __builtin_amdgcn_sched_barrier(0);
}

__device__ __forceinline__ float sigmoid_f(float x) {
    x = fminf(fmaxf(x, -30.f), 30.f);
    return 1.f / (1.f + __expf(-x));
}
__device__ __forceinline__ float tanh_f(float x) {
    x = fminf(fmaxf(x, -15.f), 15.f);
    float e = __expf(2.f * x);
    return (e - 1.f) / (e + 1.f);
}

__global__ __launch_bounds__(THREADS)
void gru_fused(const float* __restrict__ inp, const float* __restrict__ Wk,
               const float* __restrict__ Rk,  const float* __restrict__ bias,
               const float* __restrict__ W1,  const float* __restrict__ b1,
               const float* __restrict__ gam, const float* __restrict__ bet,
               const float* __restrict__ mmn, const float* __restrict__ mvr,
               const float* __restrict__ W2,  const float* __restrict__ b2p,
               const float* __restrict__ Wsh, float* __restrict__ out,
               char* __restrict__ ws)
{
    __shared__ __align__(16) f16 Bl[KTOT * 48];   // 61440 B: [R;Wk] slice as B-fragments
    __shared__ float red[4096];                    // 16384 B: reductions
    __shared__ __align__(8) f16 htile[256];        // this wg's 16x16 h-output tile

    const int tid  = threadIdx.x;
    const int g    = blockIdx.x & (NG - 1);   // group; bid%8 -> likely XCD-local
    const int wgk  = blockIdx.x >> 3;         // rank within group, 0..31
    const int lane = tid & 63;
    const int wave = tid >> 6;
    const int j0   = wgk * GC;                // first gate column owned

    unsigned* ctr   = (unsigned*)(ws + WS_CTR);
    unsigned* flg   = (unsigned*)(ws + WS_FLG);
    f16*      hring = (f16*)(ws + WS_HRING);
    float*    smw   = (float*)(ws + WS_SM);
    float*    hpart = (float*)(ws + WS_HPART);

    // ---- stage B = [R; Wk] gate-col slice (48 cols: z,r,h) into LDS as f16 frags ----
    for (int idx = tid; idx < KTOT * 48; idx += THREADS) {
        int kk  = idx / 48;
        int c   = idx - kk * 48;
        int col = (c >> 4) * HID + j0 + (c & 15);
        float v = (kk < HID) ? Rk[(size_t)kk * 1536 + col]
                             : Wk[(size_t)(kk - HID) * 1536 + col];
        Bl[((size_t)(kk >> 3) * 48 + c) * 8 + (kk & 7)] = (f16)v;
    }

    // ---- shock mean: wg with wgk<16 computes batch row g*16+wgk ----
    if (wgk < MB) {
        int b = g * MB + wgk;
        float a = 0.f;
        for (int t = tid; t < SEQL; t += THREADS)
            a += inp[((size_t)b * SEQL + t) * ROWSTR + FEA];
        red[tid] = a;
        __syncthreads();
        for (int s = THREADS / 2; s > 0; s >>= 1) {
            if (tid < s) red[tid] += red[tid + s];
            __syncthreads();
        }
        if (tid == 0) smw[b] = red[0] * (1.f / SEQL);
    }

    // per-thread gate constants; thread -> (brow=tid>>4, col=tid&15)
    const int brow = tid >> 4;
    const int jcol = j0 + (tid & 15);
    const float bZ  = bias[jcol]           + bias[1536 + jcol];
    const float bR  = bias[512 + jcol]     + bias[1536 + 512 + jcol];
    const float bXH = bias[1024 + jcol];                   // input bias, cand
    const float bHH = bias[1536 + 1024 + jcol];            // recurrent bias, cand

    const int arow  = lane & 15;    // A-frag row (batch row within block)
    const int ahalf = lane >> 4;    // A-frag k-subchunk

    float xa[4][8];                 // wave 3: prefetched x floats for current step
    if (wave == 3) {
        const float* xb = inp + ((size_t)(g * MB + arow) * SEQL + 0) * ROWSTR + ahalf * 8;
        #pragma unroll
        for (int s = 0; s < 4; ++s)
            #pragma unroll
            for (int q = 0; q < 8; ++q)
                xa[s][q] = xb[s * 32 + q];
    }

    float hold = 0.f;               // this thread's own h element (h0 = 0)
    __syncthreads();                // Bl ready

    for (int t = 0; t < SEQL; ++t) {
        const int cur = t & 1;
        const f16* hb = hring + ((size_t)cur * NG + g) * MB * HID
                              + (size_t)arow * HID + ahalf * 8;

        f32x4 aZ = {0,0,0,0}, aR = {0,0,0,0}, aH = {0,0,0,0}, aX = {0,0,0,0};

        if (wave < 3) {             // k-steps 5w..5w+4, all from h
            f16x8 af[5];
            #pragma unroll
            for (int s = 0; s < 5; ++s)
                af[s] = ld_h16(hb + (wave * 5 + s) * 32);   // batched coherent loads
            wait_vm0();                                      // ONE drain for all 5
            #pragma unroll
            for (int s = 0; s < 5; ++s) {
                int ks = wave * 5 + s;
                const f16x8* bp = ((const f16x8*)Bl) + (ks * 4 + ahalf) * 48 + (lane & 15);
                f16x8 bz = bp[0], br = bp[16], bh = bp[32];
                aZ = __builtin_amdgcn_mfma_f32_16x16x32_f16(af[s], bz, aZ, 0, 0, 0);
                aR = __builtin_amdgcn_mfma_f32_16x16x32_f16(af[s], br, aR, 0, 0, 0);
                aH = __builtin_amdgcn_mfma_f32_16x16x32_f16(af[s], bh, aH, 0, 0, 0);
            }
        } else {                    // wave 3: k-step 15 from h, 16..19 from x
            f16x8 af0 = ld_h16(hb + 15 * 32);
            f16x8 afx[4];
            #pragma unroll
            for (int s = 0; s < 4; ++s) {
                f16x8 a;
                #pragma unroll
                for (int q = 0; q < 8; ++q) a[q] = (f16)xa[s][q];
                afx[s] = a;
            }
            wait_vm0();             // af0 ready (x prefetch for t+1 happens later)
            {
                const f16x8* bp = ((const f16x8*)Bl) + (15 * 4 + ahalf) * 48 + (lane & 15);
                aZ = __builtin_amdgcn_mfma_f32_16x16x32_f16(af0, bp[0],  aZ, 0, 0, 0);
                aR = __builtin_amdgcn_mfma_f32_16x16x32_f16(af0, bp[16], aR, 0, 0, 0);
                aH = __builtin_amdgcn_mfma_f32_16x16x32_f16(af0, bp[32], aH, 0, 0, 0);
            }
            #pragma unroll
            for (int s = 0; s < 4; ++s) {
                int ks = 16 + s;
                const f16x8* bp = ((const f16x8*)Bl) + (ks * 4 + ahalf) * 48 + (lane & 15);
                aZ = __builtin_amdgcn_mfma_f32_16x16x32_f16(afx[s], bp[0],  aZ, 0, 0, 0);
                aR = __builtin_amdgcn_mfma_f32_16x16x32_f16(afx[s], bp[16], aR, 0, 0, 0);
                aX = __builtin_amdgcn_mfma_f32_16x16x32_f16(afx[s], bp[32], aX, 0, 0, 0);
            }
        }

        // stash K-split partials: D layout col=lane&15, row=(lane>>4)*4+i
        #pragma unroll
        for (int i = 0; i < 4; ++i) {
            int ridx = (ahalf * 4 + i) * 16 + (lane & 15);
            red[wave * 1024 +       ridx] = aZ[i];
            red[wave * 1024 + 256 + ridx] = aR[i];
            red[wave * 1024 + 512 + ridx] = aH[i];
        }
        if (wave == 3) {
            #pragma unroll
            for (int i = 0; i < 4; ++i) {
                int ridx = (ahalf * 4 + i) * 16 + (lane & 15);
                red[3 * 1024 + 768 + ridx] = aX[i];
            }
            {   // prefetch next step's x (plain cached loads; drained by next wait_vm0)
                int tt = (t + 1 < SEQL) ? t + 1 : SEQL - 1;
                const float* xb = inp + ((size_t)(g * MB + arow) * SEQL + tt) * ROWSTR + ahalf * 8;
                #pragma unroll
                for (int s = 0; s < 4; ++s)
                    #pragma unroll
                    for (int q = 0; q < 8; ++q)
                        xa[s][q] = xb[s * 32 + q];
            }
        }
        __syncthreads();

        // reduce + gates; thread owns element (brow, jcol); ridx identity == tid
        float zp = red[tid] + red[1024 + tid] + red[2048 + tid] + red[3072 + tid];
        float rp = red[256 + tid] + red[1280 + tid] + red[2304 + tid] + red[3328 + tid];
        float hp = red[512 + tid] + red[1536 + tid] + red[2560 + tid] + red[3584 + tid];
        float xp = red[3840 + tid];

        float z = sigmoid_f(zp + bZ);
        float r = sigmoid_f(rp + bR);
        float hcand = tanh_f((xp + bXH) + r * (hp + bHH));
        float hnew = z * hold + (1.f - z) * hcand;
        f16 h16 = (f16)hnew;
        hold = (float)h16;
        htile[brow * 16 + (tid & 15)] = h16;   // gather for wide coherent stores
        __syncthreads();

        // wave 0: publish tile (64 x 8B coherent stores), drain, flag, poll
        if (tid < 64) {
            int row = tid >> 2, q = tid & 3;
            unsigned long long val = *(const unsigned long long*)(htile + row * 16 + q * 4);
            st_h64(hring + (((size_t)(cur ^ 1) * NG + g) * MB + row) * HID + j0 + q * 4, val);
        }
        if (wave == 0) {
            asm volatile("s_waitcnt vmcnt(0)" ::: "memory");   // h-stores at coherence point
            if (lane == 0) st_flag(flg + g * 32 + wgk, (unsigned)(t + 1));
            const unsigned want = (unsigned)(t + 1);
            for (;;) {
                unsigned v = ld_flag(flg + g * 32 + (lane & 31));
                if (__all((int)(v >= want))) break;
            }
        }
        __syncthreads();
    }

    // ---- head: state=(h + shock_mean*W_shock); relu(state@W1+b1); BN; @W2+b2 ----
    // final h is in ring slot 0 (t=511 wrote cur^1 = 0); read via coherent loads
    const unsigned long long* hfq = (const unsigned long long*)
        (hring + ((size_t)g * MB + brow) * HID);
    const int sub = tid & 15;
    const int c0 = wgk * 2;          // this wg's two DENSE1 columns
    float p0 = 0.f, p1 = 0.f, w0 = 0.f, w1 = 0.f;
    for (int c8 = 0; c8 < 8; ++c8) {
        H4 x; x.u = AT_LD(hfq + sub * 8 + c8);
        #pragma unroll
        for (int e = 0; e < 4; ++e) {
            int k = sub * 32 + c8 * 4 + e;
            float hv = (float)x.h[e];
            float a0 = W1[(size_t)k * DEN1 + c0];
            float a1 = W1[(size_t)k * DEN1 + c0 + 1];
            p0 += hv * a0; p1 += hv * a1; w0 += a0; w1 += a1;
        }
    }
    red[tid] = p0; red[256 + tid] = w0; red[512 + tid] = p1; red[768 + tid] = w1;
    __syncthreads();
    if (tid < 32) {
        int b = tid >> 1, cc = tid & 1;
        int c = c0 + cc;
        float dot = 0.f, wsum = 0.f;
        for (int i = 0; i < 16; ++i) {
            dot  += red[cc * 512 + b * 16 + i];
            wsum += red[cc * 512 + 256 + b * 16 + i];
        }
        float sW = smw[g * MB + b] * Wsh[0];
        float d = dot + sW * wsum + b1[c];
        d = fmaxf(d, 0.f);
        d = (d - mmn[c]) * rsqrtf(mvr[c] + 0.001f) * gam[c] + bet[c];
        red[1024 + tid] = d * W2[c];
    }
    __syncthreads();
    if (tid < MB)
        hpart[((size_t)g * WPG + wgk) * MB + tid] = red[1024 + tid * 2] + red[1024 + tid * 2 + 1];
    __syncthreads();
    // final heavy barrier (once): full fences so plain loads of smw/hpart are fresh
    if (tid == 0) {
        __builtin_amdgcn_fence(__ATOMIC_RELEASE, "agent");
        unsigned* c9 = ctr + g;
        unsigned old = __hip_atomic_fetch_add(c9, 1u, __ATOMIC_RELAXED, __HIP_MEMORY_SCOPE_AGENT);
        if (old != WPG - 1)
            while (__hip_atomic_load(c9, __ATOMIC_RELAXED, __HIP_MEMORY_SCOPE_AGENT) < WPG) {}
        __builtin_amdgcn_fence(__ATOMIC_ACQUIRE, "agent");
    }
    __syncthreads();
    if (wgk == 0 && tid < MB) {
        float o = b2p[0];
        for (int k = 0; k < WPG; ++k)       // fixed order -> deterministic
            o += hpart[((size_t)g * WPG + k) * MB + tid];
        out[g * MB + tid] = o;
    }
}

extern "C" void kernel_launch(void* const* d_in, const int* in_sizes, int n_in,
                              void* d_out, int out_size, void* d_ws, size_t ws_size,
                              hipStream_t stream) {
    (void)in_sizes; (void)n_in; (void)out_size; (void)ws_size;
    const float* inp  = (const float*)d_in[0];
    const float* Wk   = (const float*)d_in[1];
    const float* Rk   = (const float*)d_in[2];
    const float* bias = (const float*)d_in[3];
    const float* W1   = (const float*)d_in[4];
    const float* b1   = (const float*)d_in[5];
    const float* gam  = (const float*)d_in[6];
    const float* bet  = (const float*)d_in[7];
    const float* mmn  = (const float*)d_in[8];
    const float* mvr  = (const float*)d_in[9];
    const float* W2   = (const float*)d_in[10];
    const float* b2p  = (const float*)d_in[11];
    const float* Wsh  = (const float*)d_in[12];

    hipMemsetAsync(d_ws, 0, WS_END, stream);   // flags/counters + h0 = 0, every launch
    hipLaunchKernelGGL(gru_fused, dim3(NG * WPG), dim3(THREADS), 0, stream,
                       inp, Wk, Rk, bias, W1, b1, gam, bet, mmn, mvr, W2, b2p, Wsh,
                       (float*)d_out, (char*)d_ws);
}